// Round 15
// baseline (360.990 us; speedup 1.0000x reference)
//
#include <hip/hip_runtime.h>
#include <hip/hip_bf16.h>

// DiagonalWindowAttention (v12: split attn/proj; attn at 4 blocks/CU).
//   build_comb : comb[mi][n][q][k] = mask + rel-pos bias (d_ws)
//   dwa_attn   : grid nw, 256 thr, LB(256,4), LDS 35 KB -> 4 blk/CU (16 waves):
//                LN stats; per head {comb->sacc, load+LN+stage Q/K/VT,
//                BAR(lgkm), QK^T MFMA (C=sacc), softmax, P over Q0, PV MFMA,
//                PRS transpose, coalesced pre store (no vmcnt drain)}.
//   dwa_proj   : grid nw, LB(256,3): pre[256][96]bf16 @ W^T + bias,
//                inverse grouping stores (r8-validated mapping).
//   fallback   : v11 fused kernel when ws too small.
//
// token grouping: p = wh*8+ww, s = sh*2+sw, seq g = wh*32+sh*16+ww*2+sw

#define TPB 256

// LDS byte offsets (attn)
#define Q0   0        // [64][64] bf16 swizzled (8 KB); P overlays after QK^T
#define K0   8192
#define VT0  16384    // V^T per head (8 KB), SV-swizzled
#define PRS0 24576    // [2][256][8] bf16 transpose staging (8 KB), wave-private
#define GA0  32768    // gamma fp32 [4][96]
#define BE0  34304    // beta  fp32 [4][96]
#define ATTN_LDS 35840

typedef __attribute__((ext_vector_type(8))) short short8;
typedef __attribute__((ext_vector_type(4))) float f32x4;

union FRAG { uint4 u4; short8 s8; unsigned short us[8]; };

__device__ __forceinline__ int seq_of(int p, int s) {
    return ((p >> 3) << 5) | ((s >> 1) << 4) | ((p & 7) << 1) | (s & 1);
}

#define SWZ(row, slot) (((row) << 7) + ((((slot) ^ ((row) & 7))) << 4))
#define SVK(n) (((n) ^ ((n) >> 3)) & 7)

#define LGKM_FENCE() do { \
    asm volatile("s_waitcnt lgkmcnt(0)" ::: "memory"); \
    __builtin_amdgcn_sched_barrier(0); } while (0)

#define BAR_STAGE() do { \
    asm volatile("s_waitcnt lgkmcnt(0)" ::: "memory"); \
    __builtin_amdgcn_sched_barrier(0); \
    __builtin_amdgcn_s_barrier(); \
    __builtin_amdgcn_sched_barrier(0); } while (0)

#define BAR_WAR() do { \
    __builtin_amdgcn_sched_barrier(0); \
    __builtin_amdgcn_s_barrier(); \
    __builtin_amdgcn_sched_barrier(0); } while (0)

__device__ __forceinline__ unsigned short f2b(float x) {
    union { __hip_bfloat16 h; unsigned short u; } z;
    z.h = __float2bfloat16(x);
    return z.u;
}

__device__ __forceinline__ uint4 pack8(const float* v) {
    union { uint4 u4; unsigned short us[8]; } z;
#pragma unroll
    for (int i = 0; i < 8; ++i) z.us[i] = f2b(v[i]);
    return z.u4;
}

// ---------------- pre-kernel: comb = mask + rel-pos bias ----------------
__global__ void build_comb(const float* __restrict__ gmask,
                           const float* __restrict__ gbt,
                           float* __restrict__ comb) {
    const int b = blockIdx.x;            // b = mi*6 + n
    const int mi = b / 6, n = b - mi * 6;
    const int t = threadIdx.x;
    const float* mrow = gmask + (size_t)mi * 4096;
    float* crow = comb + (size_t)b * 4096;
#pragma unroll
    for (int e = 0; e < 4096; e += TPB) {
        const int i = e + t;
        const int q = i >> 6, k = i & 63;
        const int idx = ((q >> 3) - (k >> 3) + 7) * 15 + ((q & 7) - (k & 7) + 7);
        crow[i] = mrow[i] + gbt[idx * 6 + n];
    }
}

// ======================= split path: attention kernel =======================
__global__ __launch_bounds__(TPB, 4)
void dwa_attn(const float* __restrict__ gq,
              const float* __restrict__ gk,
              const float* __restrict__ gv,
              const float* __restrict__ ggamma,
              const float* __restrict__ gbeta,
              const float* __restrict__ comb,
              __hip_bfloat16* __restrict__ gpre,
              int nwm)
{
    __shared__ __align__(16) unsigned char Lraw[ATTN_LDS];
    char* L = (char*)Lraw;

    const int w = blockIdx.x;
    const int t = threadIdx.x;
    const int lane = t & 63, wv = t >> 6;
    const int r15 = lane & 15, gsl = lane >> 4;

    const int p_a = t >> 2, s_a = t & 3;
    const int g_a = seq_of(p_a, s_a);
    const size_t rowbase = ((size_t)w * 256 + g_a) * 96;
    const int qr0 = (wv << 4) + (gsl << 2);
    const f32x4 zf = {0.f, 0.f, 0.f, 0.f};

    float* s_ga = (float*)(L + GA0);
    float* s_be = (float*)(L + BE0);

    // ---------- prologue: LN stats (regs) + gamma/beta stage ----------
    float mu, rs;
    {
        const float4* qr4 = (const float4*)(gq + rowbase);
        float sum = 0.f, ssq = 0.f;
#pragma unroll
        for (int i = 0; i < 24; ++i) {
            float4 x = qr4[i];
            sum += (x.x + x.y) + (x.z + x.w);
            ssq += (x.x * x.x + x.y * x.y) + (x.z * x.z + x.w * x.w);
        }
        sum += __shfl_xor(sum, 1); ssq += __shfl_xor(ssq, 1);
        sum += __shfl_xor(sum, 2); ssq += __shfl_xor(ssq, 2);
        mu = sum * (1.f / 384.f);
        rs = rsqrtf(ssq * (1.f / 384.f) - mu * mu + 1e-5f);
    }
    for (int i = t; i < 384; i += TPB) {
        s_ga[i] = ggamma[i];
        s_be[i] = gbeta[i];
    }
    BAR_STAGE();

    // -------------------------- head loop --------------------------
#pragma unroll 1
    for (int n = 0; n < 6; ++n) {
        // comb -> sacc (issued first; drained together with qkv by staging)
        f32x4 sacc[4];
        {
            const float* cb = comb + (size_t)((w % nwm) * 6 + n) * 4096;
#pragma unroll
            for (int tile = 0; tile < 4; ++tile)
#pragma unroll
                for (int r = 0; r < 4; ++r)
                    sacc[tile][r] = cb[((qr0 + r) << 6) + (tile << 4) + r15];
        }
        // load q/k/v (this head), LN q, pack, stage
        {
            const float4* qp_ = (const float4*)(gq + rowbase + n * 16);
            const float4* kp_ = (const float4*)(gk + rowbase + n * 16);
            const float4* vp_ = (const float4*)(gv + rowbase + n * 16);
            float xq[16], xk[16], xv[16];
#pragma unroll
            for (int i = 0; i < 4; ++i) {
                float4 a = qp_[i], b = kp_[i], c = vp_[i];
                xq[4*i+0]=a.x; xq[4*i+1]=a.y; xq[4*i+2]=a.z; xq[4*i+3]=a.w;
                xk[4*i+0]=b.x; xk[4*i+1]=b.y; xk[4*i+2]=b.z; xk[4*i+3]=b.w;
                xv[4*i+0]=c.x; xv[4*i+1]=c.y; xv[4*i+2]=c.z; xv[4*i+3]=c.w;
            }
            const float* ga_ = s_ga + s_a * 96 + n * 16;
            const float* be_ = s_be + s_a * 96 + n * 16;
#pragma unroll
            for (int i = 0; i < 16; ++i)
                xq[i] = ((xq[i] - mu) * rs * ga_[i] + be_[i]) * 0.125f;
            *(uint4*)(L + Q0 + SWZ(p_a, s_a * 2))     = pack8(xq);
            *(uint4*)(L + Q0 + SWZ(p_a, s_a * 2 + 1)) = pack8(xq + 8);
            *(uint4*)(L + K0 + SWZ(p_a, s_a * 2))     = pack8(xk);
            *(uint4*)(L + K0 + SWZ(p_a, s_a * 2 + 1)) = pack8(xk + 8);
#pragma unroll
            for (int c = 0; c < 16; ++c) {
                const int np_ = s_a * 16 + c;
                *(unsigned short*)(L + VT0 + (np_ << 7) +
                    (((p_a >> 3) ^ SVK(np_)) << 4) + ((p_a & 7) << 1)) = f2b(xv[c]);
            }
        }
        BAR_STAGE();

        // QK^T (C = sacc)
        {
            FRAG a0, a1;
            a0.u4 = *(const uint4*)(L + Q0 + SWZ(wv * 16 + r15, gsl));
            a1.u4 = *(const uint4*)(L + Q0 + SWZ(wv * 16 + r15, 4 + gsl));
#pragma unroll
            for (int tile = 0; tile < 4; ++tile) {
                FRAG b0, b1;
                b0.u4 = *(const uint4*)(L + K0 + SWZ(tile * 16 + r15, gsl));
                b1.u4 = *(const uint4*)(L + K0 + SWZ(tile * 16 + r15, 4 + gsl));
                sacc[tile] = __builtin_amdgcn_mfma_f32_16x16x32_bf16(a0.s8, b0.s8, sacc[tile], 0, 0, 0);
                sacc[tile] = __builtin_amdgcn_mfma_f32_16x16x32_bf16(a1.s8, b1.s8, sacc[tile], 0, 0, 0);
            }
        }

        // softmax in place; P overlays Q0 (wave-private rows)
#pragma unroll
        for (int r = 0; r < 4; ++r) {
            const int q = qr0 + r;
            float mx = fmaxf(fmaxf(sacc[0][r], sacc[1][r]),
                             fmaxf(sacc[2][r], sacc[3][r]));
            mx = fmaxf(mx, __shfl_xor(mx, 1));
            mx = fmaxf(mx, __shfl_xor(mx, 2));
            mx = fmaxf(mx, __shfl_xor(mx, 4));
            mx = fmaxf(mx, __shfl_xor(mx, 8));
            float sm = 0.f;
#pragma unroll
            for (int tile = 0; tile < 4; ++tile) {
                sacc[tile][r] = __expf(sacc[tile][r] - mx);
                sm += sacc[tile][r];
            }
            sm += __shfl_xor(sm, 1);
            sm += __shfl_xor(sm, 2);
            sm += __shfl_xor(sm, 4);
            sm += __shfl_xor(sm, 8);
            const float inv = 1.0f / sm;
#pragma unroll
            for (int tile = 0; tile < 4; ++tile) {
                const int col = (tile << 4) + r15;
                *(unsigned short*)(L + Q0 + (q << 7) +
                                   (((col >> 3) ^ (q & 7)) << 4) + ((col & 7) << 1))
                    = f2b(sacc[tile][r] * inv);
            }
        }
        LGKM_FENCE();

        // PV: A = P (Q0), B = VT rows (SV swizzle)
        f32x4 oacc[4];
        {
            FRAG pa0, pa1;
            pa0.u4 = *(const uint4*)(L + Q0 + SWZ(wv * 16 + r15, gsl));
            pa1.u4 = *(const uint4*)(L + Q0 + SWZ(wv * 16 + r15, 4 + gsl));
#pragma unroll
            for (int ct = 0; ct < 4; ++ct) {
                const int nr = ct * 16 + r15;
                const int sv = SVK(nr);
                FRAG b0, b1;
                b0.u4 = *(const uint4*)(L + VT0 + (nr << 7) + ((gsl ^ sv) << 4));
                b1.u4 = *(const uint4*)(L + VT0 + (nr << 7) + (((4 + gsl) ^ sv) << 4));
                oacc[ct] = __builtin_amdgcn_mfma_f32_16x16x32_bf16(pa0.s8, b0.s8, zf, 0, 0, 0);
                oacc[ct] = __builtin_amdgcn_mfma_f32_16x16x32_bf16(pa1.s8, b1.s8, oacc[ct], 0, 0, 0);
            }
        }

        // transpose via PRS: [h2=r15>>3][tok][r15&7] (wave-private rows)
#pragma unroll
        for (int ct = 0; ct < 4; ++ct)
#pragma unroll
            for (int r = 0; r < 4; ++r) {
                const int tok = ((qr0 + r) << 2) + ct;
                *(unsigned short*)(L + PRS0 + ((r15 >> 3) << 12) + (tok << 4) +
                                   ((r15 & 7) << 1)) = f2b(oacc[ct][r]);
            }
        LGKM_FENCE();
        // coalesced pre store: thread t owns token t (same wave's rows);
        // fire-and-forget — no vmcnt drain anywhere in this kernel
        {
            uint4 lo = *(const uint4*)(L + PRS0 + (t << 4));
            uint4 hi = *(const uint4*)(L + PRS0 + 4096 + (t << 4));
            unsigned short* pb = (unsigned short*)gpre + (((size_t)w * 6 + n) << 12) + (t << 4);
            *(uint4*)(pb)     = lo;
            *(uint4*)(pb + 8) = hi;
        }
        if (n < 5) BAR_WAR();
    }
}

// ======================= split path: projection kernel =======================
__global__ __launch_bounds__(TPB, 3)
void dwa_proj(const __hip_bfloat16* __restrict__ gpre,
              const float* __restrict__ gpw,
              const float* __restrict__ gpb,
              float* __restrict__ gout)
{
    const int w = blockIdx.x;
    const int t = threadIdx.x;
    const int lane = t & 63, wv = t >> 6;
    const int r15 = lane & 15, gsl = lane >> 4;
    const f32x4 zf = {0.f, 0.f, 0.f, 0.f};

    // W B-frags: o = ct*16 + r15, k-slice = kk*32 + gsl*8
    FRAG bw[3][6];
#pragma unroll
    for (int kk = 0; kk < 3; ++kk)
#pragma unroll
        for (int ct = 0; ct < 6; ++ct) {
            const int o = (ct << 4) + r15;
            const float4* wp = (const float4*)(gpw + o * 96 + kk * 32 + (gsl << 3));
            float4 w0 = wp[0], w1 = wp[1];
            float w8[8] = {w0.x, w0.y, w0.z, w0.w, w1.x, w1.y, w1.z, w1.w};
            bw[kk][ct].u4 = pack8(w8);
        }
    float pbv[6];
#pragma unroll
    for (int ct = 0; ct < 6; ++ct) pbv[ct] = gpb[(ct << 4) + r15];

#pragma unroll
    for (int mt = 0; mt < 4; ++mt) {
        const int rowA = (wv << 6) + (mt << 4) + r15;
        FRAG A[3];
#pragma unroll
        for (int kk = 0; kk < 3; ++kk) {
            const int n = kk * 2 + (gsl >> 1);
            const int c0 = (gsl & 1) << 3;
            A[kk].u4 = *(const uint4*)((const unsigned short*)gpre +
                                       (((size_t)w * 6 + n) << 12) + (rowA << 4) + c0);
        }
        f32x4 acc[6];
#pragma unroll
        for (int ct = 0; ct < 6; ++ct) {
            acc[ct] = __builtin_amdgcn_mfma_f32_16x16x32_bf16(A[0].s8, bw[0][ct].s8, zf, 0, 0, 0);
            acc[ct] = __builtin_amdgcn_mfma_f32_16x16x32_bf16(A[1].s8, bw[1][ct].s8, acc[ct], 0, 0, 0);
            acc[ct] = __builtin_amdgcn_mfma_f32_16x16x32_bf16(A[2].s8, bw[2][ct].s8, acc[ct], 0, 0, 0);
        }
#pragma unroll
        for (int ct = 0; ct < 6; ++ct)
#pragma unroll
            for (int rr = 0; rr < 4; ++rr) {
                const int token = (wv << 6) + (mt << 4) + (gsl << 2) + rr;
                const int p = token >> 2, s = token & 3;
                const int gsq = seq_of(p, s);
                gout[((size_t)w * 256 + gsq) * 96 + (ct << 4) + r15]
                    = acc[ct][rr] + pbv[ct];
            }
    }
}

// ======================= fallback: v11 fused kernel =======================
#define FQ0   0
#define FK0   8192
#define FVT0  16384
#define FPR0  24576
#define FGA0  77824
#define FBE0  79360
#define F_LDS 80896

#define F_PREFETCH(NN, QQ, KK, VV, SS)                                         \
    {                                                                          \
        if (USE_COMB) {                                                        \
            const float* cb = comb + (size_t)((w % nwm) * 6 + (NN)) * 4096;    \
            _Pragma("unroll")                                                  \
            for (int tile = 0; tile < 4; ++tile)                               \
                _Pragma("unroll")                                              \
                for (int r = 0; r < 4; ++r)                                    \
                    SS[tile][r] = cb[((qr0 + r) << 6) + (tile << 4) + r15];    \
        } else {                                                               \
            _Pragma("unroll")                                                  \
            for (int tile = 0; tile < 4; ++tile) {                             \
                const int kpx = (tile << 4) + r15;                             \
                const int ik = kpx >> 3, jk = kpx & 7;                         \
                _Pragma("unroll")                                              \
                for (int r = 0; r < 4; ++r) {                                  \
                    const int q = qr0 + r;                                     \
                    SS[tile][r] = gbt[(((q >> 3) - ik + 7) * 15 +              \
                                      ((q & 7) - jk + 7)) * 6 + (NN)]          \
                                + gmask[mbase + (q << 6) + kpx];               \
                }                                                              \
            }                                                                  \
        }                                                                      \
        const float4* qp_ = (const float4*)(gq + rowbase + (NN) * 16);         \
        const float4* kp_ = (const float4*)(gk + rowbase + (NN) * 16);         \
        const float4* vp_ = (const float4*)(gv + rowbase + (NN) * 16);         \
        _Pragma("unroll")                                                      \
        for (int i = 0; i < 4; ++i) {                                          \
            QQ[i] = qp_[i]; KK[i] = kp_[i]; VV[i] = vp_[i];                    \
        }                                                                      \
    }

#define F_STAGE_QKV(NN, QQ, KK, VV)                                            \
    {                                                                          \
        const float* ga_ = s_ga + s_a * 96 + (NN) * 16;                        \
        const float* be_ = s_be + s_a * 96 + (NN) * 16;                        \
        float xq[16], xk[16], xv[16];                                          \
        _Pragma("unroll")                                                      \
        for (int i = 0; i < 4; ++i) {                                          \
            xq[4*i+0]=QQ[i].x; xq[4*i+1]=QQ[i].y; xq[4*i+2]=QQ[i].z; xq[4*i+3]=QQ[i].w; \
            xk[4*i+0]=KK[i].x; xk[4*i+1]=KK[i].y; xk[4*i+2]=KK[i].z; xk[4*i+3]=KK[i].w; \
            xv[4*i+0]=VV[i].x; xv[4*i+1]=VV[i].y; xv[4*i+2]=VV[i].z; xv[4*i+3]=VV[i].w; \
        }                                                                      \
        _Pragma("unroll")                                                      \
        for (int i = 0; i < 16; ++i)                                           \
            xq[i] = ((xq[i] - mu) * rs * ga_[i] + be_[i]) * 0.125f;            \
        *(uint4*)(L + FQ0 + SWZ(p_a, s_a * 2))     = pack8(xq);                \
        *(uint4*)(L + FQ0 + SWZ(p_a, s_a * 2 + 1)) = pack8(xq + 8);            \
        *(uint4*)(L + FK0 + SWZ(p_a, s_a * 2))     = pack8(xk);                \
        *(uint4*)(L + FK0 + SWZ(p_a, s_a * 2 + 1)) = pack8(xk + 8);            \
        _Pragma("unroll")                                                      \
        for (int c = 0; c < 16; ++c) {                                         \
            const int np_ = s_a * 16 + c;                                      \
            *(unsigned short*)(L + FVT0 + (np_ << 7) +                         \
                (((p_a >> 3) ^ SVK(np_)) << 4) + ((p_a & 7) << 1)) = f2b(xv[c]); \
        }                                                                      \
    }

#define F_COMPUTE_HEAD(NN, SS)                                                 \
    {                                                                          \
        {                                                                      \
            FRAG a0, a1;                                                       \
            a0.u4 = *(const uint4*)(L + FQ0 + SWZ(wv * 16 + r15, gsl));        \
            a1.u4 = *(const uint4*)(L + FQ0 + SWZ(wv * 16 + r15, 4 + gsl));    \
            _Pragma("unroll")                                                  \
            for (int tile = 0; tile < 4; ++tile) {                             \
                FRAG b0, b1;                                                   \
                b0.u4 = *(const uint4*)(L + FK0 + SWZ(tile * 16 + r15, gsl));  \
                b1.u4 = *(const uint4*)(L + FK0 + SWZ(tile * 16 + r15, 4 + gsl)); \
                SS[tile] = __builtin_amdgcn_mfma_f32_16x16x32_bf16(a0.s8, b0.s8, SS[tile], 0, 0, 0); \
                SS[tile] = __builtin_amdgcn_mfma_f32_16x16x32_bf16(a1.s8, b1.s8, SS[tile], 0, 0, 0); \
            }                                                                  \
        }                                                                      \
        _Pragma("unroll")                                                      \
        for (int r = 0; r < 4; ++r) {                                          \
            const int q = qr0 + r;                                             \
            float mx = fmaxf(fmaxf(SS[0][r], SS[1][r]), fmaxf(SS[2][r], SS[3][r])); \
            mx = fmaxf(mx, __shfl_xor(mx, 1));                                 \
            mx = fmaxf(mx, __shfl_xor(mx, 2));                                 \
            mx = fmaxf(mx, __shfl_xor(mx, 4));                                 \
            mx = fmaxf(mx, __shfl_xor(mx, 8));                                 \
            float sm = 0.f;                                                    \
            _Pragma("unroll")                                                  \
            for (int tile = 0; tile < 4; ++tile) {                             \
                SS[tile][r] = __expf(SS[tile][r] - mx);                        \
                sm += SS[tile][r];                                             \
            }                                                                  \
            sm += __shfl_xor(sm, 1);                                           \
            sm += __shfl_xor(sm, 2);                                           \
            sm += __shfl_xor(sm, 4);                                           \
            sm += __shfl_xor(sm, 8);                                           \
            const float inv = 1.0f / sm;                                       \
            _Pragma("unroll")                                                  \
            for (int tile = 0; tile < 4; ++tile) {                             \
                const int col = (tile << 4) + r15;                             \
                *(unsigned short*)(L + FQ0 + (q << 7) +                        \
                    (((col >> 3) ^ (q & 7)) << 4) + ((col & 7) << 1))          \
                    = f2b(SS[tile][r] * inv);                                  \
            }                                                                  \
        }                                                                      \
        LGKM_FENCE();                                                          \
        f32x4 oacc[4];                                                         \
        {                                                                      \
            FRAG pa0, pa1;                                                     \
            pa0.u4 = *(const uint4*)(L + FQ0 + SWZ(wv * 16 + r15, gsl));       \
            pa1.u4 = *(const uint4*)(L + FQ0 + SWZ(wv * 16 + r15, 4 + gsl));   \
            _Pragma("unroll")                                                  \
            for (int ct = 0; ct < 4; ++ct) {                                   \
                const int nr = ct * 16 + r15;                                  \
                const int sv = SVK(nr);                                        \
                FRAG b0, b1;                                                   \
                b0.u4 = *(const uint4*)(L + FVT0 + (nr << 7) + ((gsl ^ sv) << 4)); \
                b1.u4 = *(const uint4*)(L + FVT0 + (nr << 7) + (((4 + gsl) ^ sv) << 4)); \
                oacc[ct] = __builtin_amdgcn_mfma_f32_16x16x32_bf16(pa0.s8, b0.s8, zf, 0, 0, 0); \
                oacc[ct] = __builtin_amdgcn_mfma_f32_16x16x32_bf16(pa1.s8, b1.s8, oacc[ct], 0, 0, 0); \
            }                                                                  \
        }                                                                      \
        _Pragma("unroll")                                                      \
        for (int ct = 0; ct < 4; ++ct)                                         \
            _Pragma("unroll")                                                  \
            for (int r = 0; r < 4; ++r) {                                      \
                const int token = ((qr0 + r) << 2) + ct;                       \
                *(unsigned short*)(L + FPR0 + token * 208 + (((NN) << 4) + r15) * 2) \
                    = f2b(oacc[ct][r]);                                        \
            }                                                                  \
    }

template <int USE_COMB>
__global__ __launch_bounds__(TPB, 2)
void dwa_fused(const float* __restrict__ gq,
               const float* __restrict__ gk,
               const float* __restrict__ gv,
               const float* __restrict__ gmask,
               const float* __restrict__ gbt,
               const float* __restrict__ ggamma,
               const float* __restrict__ gbeta,
               const float* __restrict__ gpw,
               const float* __restrict__ gpb,
               float* __restrict__ gout,
               const float* __restrict__ comb,
               int nwm)
{
    __shared__ __align__(16) unsigned char Lraw[F_LDS];
    char* L = (char*)Lraw;

    const int w = blockIdx.x;
    const int t = threadIdx.x;
    const int lane = t & 63, wv = t >> 6;
    const int r15 = lane & 15, gsl = lane >> 4;

    const int p_a = t >> 2, s_a = t & 3;
    const int g_a = seq_of(p_a, s_a);
    const size_t rowbase = ((size_t)w * 256 + g_a) * 96;
    const int mbase = (w % nwm) * 4096;
    const int qr0 = (wv << 4) + (gsl << 2);
    const f32x4 zf = {0.f, 0.f, 0.f, 0.f};

    float* s_ga = (float*)(L + FGA0);
    float* s_be = (float*)(L + FBE0);

    float mu, rs;
    {
        const float4* qr4 = (const float4*)(gq + rowbase);
        float sum = 0.f, ssq = 0.f;
#pragma unroll
        for (int i = 0; i < 24; ++i) {
            float4 x = qr4[i];
            sum += (x.x + x.y) + (x.z + x.w);
            ssq += (x.x * x.x + x.y * x.y) + (x.z * x.z + x.w * x.w);
        }
        sum += __shfl_xor(sum, 1); ssq += __shfl_xor(ssq, 1);
        sum += __shfl_xor(sum, 2); ssq += __shfl_xor(ssq, 2);
        mu = sum * (1.f / 384.f);
        rs = rsqrtf(ssq * (1.f / 384.f) - mu * mu + 1e-5f);
    }
    for (int i = t; i < 384; i += TPB) {
        s_ga[i] = ggamma[i];
        s_be[i] = gbeta[i];
    }

    float4 qA[4], kA[4], vA[4], qB[4], kB[4], vB[4];
    f32x4 sA[4], sB[4];

    F_PREFETCH(0, qA, kA, vA, sA);
    BAR_STAGE();

#pragma unroll 1
    for (int nh = 0; nh < 3; ++nh) {
        const int n0 = nh * 2;
        F_STAGE_QKV(n0, qA, kA, vA);
        F_PREFETCH(n0 + 1, qB, kB, vB, sB);
        BAR_STAGE();
        F_COMPUTE_HEAD(n0, sA);
        BAR_WAR();
        F_STAGE_QKV(n0 + 1, qB, kB, vB);
        if (nh < 2) F_PREFETCH(n0 + 2, qA, kA, vA, sA);
        BAR_STAGE();
        F_COMPUTE_HEAD(n0 + 1, sB);
        if (nh < 2) BAR_WAR();
    }

    LGKM_FENCE();
    {
        FRAG bw[3][6];
#pragma unroll
        for (int kk = 0; kk < 3; ++kk)
#pragma unroll
            for (int ct = 0; ct < 6; ++ct) {
                const int o = (ct << 4) + r15;
                const float4* wp = (const float4*)(gpw + o * 96 + kk * 32 + (gsl << 3));
                float4 w0 = wp[0], w1 = wp[1];
                float w8[8] = {w0.x, w0.y, w0.z, w0.w, w1.x, w1.y, w1.z, w1.w};
                bw[kk][ct].u4 = pack8(w8);
            }
        float pbv[6];
#pragma unroll
        for (int ct = 0; ct < 6; ++ct) pbv[ct] = gpb[(ct << 4) + r15];

#pragma unroll
        for (int mt = 0; mt < 4; ++mt) {
            const int rowA = (wv << 6) + (mt << 4) + r15;
            FRAG A[3];
#pragma unroll
            for (int kk = 0; kk < 3; ++kk)
                A[kk].u4 = *(const uint4*)(L + FPR0 + rowA * 208 + kk * 64 + (gsl << 4));
            f32x4 acc[6];
#pragma unroll
            for (int ct = 0; ct < 6; ++ct) {
                acc[ct] = __builtin_amdgcn_mfma_f32_16x16x32_bf16(A[0].s8, bw[0][ct].s8, zf, 0, 0, 0);
                acc[ct] = __builtin_amdgcn_mfma_f32_16x16x32_bf16(A[1].s8, bw[1][ct].s8, acc[ct], 0, 0, 0);
                acc[ct] = __builtin_amdgcn_mfma_f32_16x16x32_bf16(A[2].s8, bw[2][ct].s8, acc[ct], 0, 0, 0);
            }
#pragma unroll
            for (int ct = 0; ct < 6; ++ct)
#pragma unroll
                for (int rr = 0; rr < 4; ++rr) {
                    const int token = (wv << 6) + (mt << 4) + (gsl << 2) + rr;
                    const int p = token >> 2, s = token & 3;
                    const int gsq = seq_of(p, s);
                    gout[((size_t)w * 256 + gsq) * 96 + (ct << 4) + r15]
                        = acc[ct][rr] + pbv[ct];
                }
        }
    }
}

extern "C" void kernel_launch(void* const* d_in, const int* in_sizes, int n_in,
                              void* d_out, int out_size, void* d_ws, size_t ws_size,
                              hipStream_t stream) {
    const float* gq     = (const float*)d_in[0];
    const float* gk     = (const float*)d_in[1];
    const float* gv     = (const float*)d_in[2];
    const float* gmask  = (const float*)d_in[3];
    const float* gbt    = (const float*)d_in[4];
    const float* ggamma = (const float*)d_in[5];
    const float* gbeta  = (const float*)d_in[6];
    const float* gpw    = (const float*)d_in[7];
    const float* gpb    = (const float*)d_in[8];
    float* gout = (float*)d_out;

    const int nw  = in_sizes[0] / (256 * 96);
    const int nwm = in_sizes[3] / (64 * 64);
    const size_t comb_bytes = (size_t)nwm * 6 * 4096 * sizeof(float);
    const size_t comb_pad   = (comb_bytes + 255) & ~(size_t)255;
    const size_t pre_bytes  = (size_t)nw * 6 * 256 * 16 * sizeof(__hip_bfloat16);

    if (ws_size >= comb_pad + pre_bytes) {
        float* comb = (float*)d_ws;
        __hip_bfloat16* gpre = (__hip_bfloat16*)((char*)d_ws + comb_pad);
        build_comb<<<nwm * 6, TPB, 0, stream>>>(gmask, gbt, comb);
        dwa_attn<<<nw, TPB, 0, stream>>>(gq, gk, gv, ggamma, gbeta, comb, gpre, nwm);
        dwa_proj<<<nw, TPB, 0, stream>>>(gpre, gpw, gpb, gout);
    } else if (ws_size >= comb_bytes) {
        float* comb = (float*)d_ws;
        build_comb<<<nwm * 6, TPB, 0, stream>>>(gmask, gbt, comb);
        dwa_fused<1><<<nw, TPB, 0, stream>>>(gq, gk, gv, gmask, gbt, ggamma, gbeta,
                                             gpw, gpb, gout, comb, nwm);
    } else {
        dwa_fused<0><<<nw, TPB, 0, stream>>>(gq, gk, gv, gmask, gbt, ggamma, gbeta,
                                             gpw, gpb, gout, (const float*)nullptr, nwm);
    }
}